// Round 1
// baseline (310.630 us; speedup 1.0000x reference)
//
#include <hip/hip_runtime.h>

typedef short short8 __attribute__((ext_vector_type(8)));
typedef float f32x4 __attribute__((ext_vector_type(4)));

// ---------------- bf16 helpers ----------------

__device__ inline unsigned short f2bf(float f) {
    union { float f; unsigned u; } v; v.f = f;
    unsigned r = v.u + 0x7fffu + ((v.u >> 16) & 1u);
    return (unsigned short)(r >> 16);
}
__device__ inline unsigned pack2(float a, float b) {
    return (unsigned)f2bf(a) | ((unsigned)f2bf(b) << 16);
}
__device__ inline float bflo(unsigned u) { union { unsigned q; float f; } c; c.q = u << 16; return c.f; }
__device__ inline float bfhi(unsigned u) { union { unsigned q; float f; } c; c.q = u & 0xffff0000u; return c.f; }

#define ACC8(vv)                                     \
    acc[0] += bflo(vv.x); acc[1] += bfhi(vv.x);      \
    acc[2] += bflo(vv.y); acc[3] += bfhi(vv.y);      \
    acc[4] += bflo(vv.z); acc[5] += bfhi(vv.z);      \
    acc[6] += bflo(vv.w); acc[7] += bfhi(vv.w);

// ---------------- edge-parallel gather core ----------------
// Each thread owns a contiguous run [j0,jend) of the block's CSR-sorted edge list
// and one 8-element column chunk c. Register-accumulates; flushes to the fp32 LDS
// tile (ds_add_f32) whenever the dst node changes. Perfectly balanced across
// threads; 8 independent row loads in flight per thread.

template <int PITCH, int TPN, typename F>
__device__ __forceinline__ void edge_gather(float (*As)[PITCH], const int* __restrict__ rpl,
                                            const uint4* __restrict__ x, int c,
                                            int j0, int jend, int nd, F geti) {
    float acc[8] = {0.f, 0.f, 0.f, 0.f, 0.f, 0.f, 0.f, 0.f};
    int nxt = rpl[nd + 1];
    int k = j0;
    for (; k + 8 <= jend; k += 8) {
        uint4 v[8];
#pragma unroll
        for (int u = 0; u < 8; u++) v[u] = x[(size_t)geti(k + u) * TPN + c];
#pragma unroll
        for (int u = 0; u < 8; u++) {
            while (k + u >= nxt) {
#pragma unroll
                for (int i = 0; i < 8; i++) { atomicAdd(&As[nd][c * 8 + i], acc[i]); acc[i] = 0.f; }
                ++nd; nxt = rpl[nd + 1];
            }
            ACC8(v[u])
        }
    }
    for (; k < jend; ++k) {
        uint4 v0 = x[(size_t)geti(k) * TPN + c];
        while (k >= nxt) {
#pragma unroll
            for (int i = 0; i < 8; i++) { atomicAdd(&As[nd][c * 8 + i], acc[i]); acc[i] = 0.f; }
            ++nd; nxt = rpl[nd + 1];
        }
        ACC8(v0)
    }
#pragma unroll
    for (int i = 0; i < 8; i++) atomicAdd(&As[nd][c * 8 + i], acc[i]);
}

// largest nd with rpl[nd] <= j (rpl non-decreasing). S0 = 8 for 16 nodes, 16 for 32.
template <int S0>
__device__ __forceinline__ int ub_search(const int* __restrict__ rpl, int j) {
    int nd = 0;
#pragma unroll
    for (int s = S0; s >= 1; s >>= 1)
        if (rpl[nd + s] <= j) nd += s;
    return nd;
}

// ---------------- CSR build: atomic-free two-level bucket sort (unchanged) ----------------

#define EPB 2048
#define NE 8
#define BSH 9
#define MAXBKT 128
#define DCAP 10240

__global__ __launch_bounds__(256) void mega1(const int* __restrict__ dst, int* __restrict__ cnt2d,
                                             int e, int nbkt, int nblk,
                                             const float4* __restrict__ feat, uint2* __restrict__ featb,
                                             int cvtb, int nf4,
                                             const float* __restrict__ W1, const float* __restrict__ Wh,
                                             const float* __restrict__ Wo,
                                             unsigned short* __restrict__ W1t, unsigned short* __restrict__ Wht,
                                             unsigned short* __restrict__ Wot) {
    __shared__ int hist[MAXBKT];
    int t = threadIdx.x, b = blockIdx.x;
    if (b < nblk) {
        for (int j = t; j < nbkt; j += 256) hist[j] = 0;
        __syncthreads();
        int base = b * EPB;
#pragma unroll
        for (int j = 0; j < NE; j++) {
            int idx = base + t + 256 * j;
            if (idx < e) atomicAdd(&hist[dst[idx] >> BSH], 1);
        }
        __syncthreads();
        for (int j = t; j < nbkt; j += 256) cnt2d[j * nblk + b] = hist[j];
    } else if (b < nblk + cvtb) {
        int i = (b - nblk) * 256 + t;
        if (i < nf4) {
            float4 v = feat[i];
            featb[i] = make_uint2(pack2(v.x, v.y), pack2(v.z, v.w));
        }
    } else {
        int i = (b - nblk - cvtb) * 256 + t;
        if (i < 16384) {
            int k = i >> 7, nn = i & 127;
            W1t[nn * 128 + k] = f2bf(W1[i]);
        } else if (i < 32768) {
            int j = i - 16384, k = j >> 7, nn = j & 127;
            Wht[nn * 128 + k] = f2bf(Wh[j]);
        } else if (i < 40960) {
            int j = i - 32768, k = j >> 6, nn = j & 63;
            Wot[nn * 128 + k] = f2bf(Wo[j]);
        }
    }
}

__global__ __launch_bounds__(512) void scanB1(int* __restrict__ cnt2d, int* __restrict__ totals, int nblk) {
    __shared__ int s[512];
    int t = threadIdx.x, b = blockIdx.x;
    int v = (t < nblk) ? cnt2d[b * nblk + t] : 0;
    s[t] = v;
    __syncthreads();
    for (int off = 1; off < 512; off <<= 1) {
        int u = (t >= off) ? s[t - off] : 0;
        __syncthreads();
        s[t] += u;
        __syncthreads();
    }
    if (t < nblk) cnt2d[b * nblk + t] = s[t] - v;
    if (t == nblk - 1) totals[b] = s[t];
}

__global__ __launch_bounds__(128) void scanB2(const int* __restrict__ totals, int* __restrict__ bbase,
                                              int* __restrict__ row_ptr, int nbkt, int n, int e) {
    __shared__ int s[128];
    int t = threadIdx.x;
    int v = (t < nbkt) ? totals[t] : 0;
    s[t] = v;
    __syncthreads();
    for (int off = 1; off < 128; off <<= 1) {
        int u = (t >= off) ? s[t - off] : 0;
        __syncthreads();
        s[t] += u;
        __syncthreads();
    }
    if (t < nbkt) bbase[t] = s[t] - v;
    if (t == 0) row_ptr[n] = e;
}

__global__ __launch_bounds__(256) void binC(const int* __restrict__ src, const int* __restrict__ dst,
                                            const int* __restrict__ cnt2d, const int* __restrict__ bbase,
                                            unsigned* __restrict__ pairs, int e, int nbkt, int nblk) {
    __shared__ int hist[MAXBKT], loff[MAXBKT], cur[MAXBKT], gb[MAXBKT];
    __shared__ int sc[256];
    __shared__ unsigned sorted[EPB];
    int t = threadIdx.x, blk = blockIdx.x;
    for (int b = t; b < nbkt; b += 256) hist[b] = 0;
    __syncthreads();
    int base = blk * EPB;
    int cnt = min(EPB, e - base);
    unsigned packed[NE];
    int bb[NE];
#pragma unroll
    for (int j = 0; j < NE; j++) {
        int idx = base + t + 256 * j;
        bb[j] = -1;
        if (idx < e) {
            unsigned s0 = (unsigned)src[idx], d = (unsigned)dst[idx];
            int b = (int)(d >> BSH);
            bb[j] = b;
            packed[j] = s0 | ((d & ((1u << BSH) - 1)) << 16) | ((unsigned)b << 25);
            atomicAdd(&hist[b], 1);
        }
    }
    __syncthreads();
    int v = (t < nbkt) ? hist[t] : 0;
    sc[t] = v;
    __syncthreads();
    for (int off = 1; off < 256; off <<= 1) {
        int u = (t >= off) ? sc[t - off] : 0;
        __syncthreads();
        sc[t] += u;
        __syncthreads();
    }
    if (t < nbkt) {
        int ex = sc[t] - v;
        loff[t] = ex;
        cur[t] = ex;
        gb[t] = bbase[t] + cnt2d[t * nblk + blk];
    }
    __syncthreads();
#pragma unroll
    for (int j = 0; j < NE; j++) {
        if (bb[j] >= 0) {
            int r = atomicAdd(&cur[bb[j]], 1);  // LDS only
            sorted[r] = packed[j];
        }
    }
    __syncthreads();
    for (int i = t; i < cnt; i += 256) {
        unsigned w = sorted[i];
        int b = (int)(w >> 25);
        pairs[gb[b] + (i - loff[b])] = w;
    }
}

__global__ __launch_bounds__(512) void buildD(const unsigned* __restrict__ pairs,
                                              const int* __restrict__ totals, const int* __restrict__ bbase,
                                              int* __restrict__ row_ptr, unsigned short* __restrict__ csr, int n) {
    __shared__ int hist[512], off[512];
    __shared__ unsigned short lcsr[DCAP];
    int t = threadIdx.x, b = blockIdx.x;
    int cnt = totals[b], base = bbase[b];
    hist[t] = 0;
    __syncthreads();
    for (int i = t; i < cnt; i += 512)
        atomicAdd(&hist[(pairs[base + i] >> 16) & 511], 1);
    __syncthreads();
    int v = hist[t];
    off[t] = v;
    __syncthreads();
    for (int o = 1; o < 512; o <<= 1) {
        int u = (t >= o) ? off[t - o] : 0;
        __syncthreads();
        off[t] += u;
        __syncthreads();
    }
    int excl = off[t] - v;
    int node = (b << BSH) + t;
    if (node < n) row_ptr[node] = base + excl;
    __syncthreads();
    hist[t] = excl;
    __syncthreads();
    for (int i = t; i < cnt; i += 512) {
        unsigned w = pairs[base + i];
        int r = atomicAdd(&hist[(w >> 16) & 511], 1);  // LDS only
        if (r < DCAP) lcsr[r] = (unsigned short)(w & 0xFFFFu);
    }
    __syncthreads();
    int lim = min(cnt, DCAP);
    for (int i = t; i < lim; i += 512) csr[base + i] = lcsr[i];
}

// ---------------- Fused layer: edge-parallel gather + MFMA GEMM ----------------
// Block = 256 threads, 16 nodes (one MFMA row strip).
// Phase 1 threads = (edge-group g = t>>4, chunk c = t&15): each thread processes a
// contiguous 1/16 slice of the block's edges for its 8-column chunk. Lanes 0-15 of
// each quarter-wave read one contiguous 256 B row -> coalescing identical to before,
// but zero divergence and exact load balance across all 256 threads.

#define ECAP 1024   // block edge-index LDS cap; mean 256, >40 sigma headroom

template <bool SECOND>
__global__ __launch_bounds__(256) void fused_layer(
    const uint4* __restrict__ x, const int* __restrict__ row_ptr,
    const unsigned short* __restrict__ csr,
    const short8* __restrict__ Bt, const float* __restrict__ bias,
    unsigned short* __restrict__ out_h,   // !SECOND
    const short8* __restrict__ Bt2,       // SECOND
    unsigned short* __restrict__ out_y,   // SECOND
    int n) {
    __shared__ float Asf[16][140];        // fp32 accum tile; pitch 140 -> 16B-aligned rows, 2-way banks on frag reads
    __shared__ unsigned short Hs[SECOND ? 16 : 1][SECOND ? 136 : 1];
    __shared__ unsigned short eidx[ECAP];
    __shared__ int rpl[17];               // block-local row offsets (row_ptr - E0)

    int t = threadIdx.x;
    int g = t >> 4, c = t & 15;           // edge-group, chunk
    int r0 = blockIdx.x * 16;
    int node = r0 + g;                    // for self-init / GEMM rows, g doubles as node-lane

    int E0 = row_ptr[r0];                 // uniform -> scalar load
    int E1 = row_ptr[min(r0 + 16, n)];    // uniform
    int ecnt = E1 - E0;
    bool fits = (ecnt <= ECAP);
    int scnt = fits ? ecnt : ECAP;
    for (int i = t; i < scnt; i += 256) eidx[i] = csr[E0 + i];
    if (t < 17) rpl[t] = row_ptr[min(r0 + t, n)] - E0;

    // self term (1+eps)*x, eps=0 -> init tile with x row (zeros for OOB rows)
    {
        f32x4 lo = {0.f, 0.f, 0.f, 0.f}, hi = {0.f, 0.f, 0.f, 0.f};
        if (node < n) {
            uint4 s0 = x[(size_t)node * 16 + c];
            lo[0] = bflo(s0.x); lo[1] = bfhi(s0.x); lo[2] = bflo(s0.y); lo[3] = bfhi(s0.y);
            hi[0] = bflo(s0.z); hi[1] = bfhi(s0.z); hi[2] = bflo(s0.w); hi[3] = bfhi(s0.w);
        }
        *(f32x4*)&Asf[g][c * 8] = lo;
        *(f32x4*)&Asf[g][c * 8 + 4] = hi;
    }
    __syncthreads();

    // ---- Phase 1: balanced edge-parallel aggregation ----
    {
        int L = (ecnt + 15) >> 4;
        int j0 = g * L, jend = min(j0 + L, ecnt);
        if (j0 < jend) {
            int nd = ub_search<8>(rpl, j0);
            if (fits)
                edge_gather<140, 16>(Asf, rpl, x, c, j0, jend, nd,
                                     [&](int k) { return (int)eidx[k]; });
            else
                edge_gather<140, 16>(Asf, rpl, x, c, j0, jend, nd,
                                     [&](int k) { return (int)csr[E0 + k]; });
        }
    }
    __syncthreads();

    // ---- Phase 2: GEMM 16x128 @ 128x128 (A packed bf16 from fp32 tile) ----
    int wid = t >> 6, lane = t & 63;
    int lm = lane & 15, lq = lane >> 4;

    short8 a[4];
#pragma unroll
    for (int kc = 0; kc < 4; kc++) {
        const f32x4* Ar = (const f32x4*)&Asf[lm][kc * 32 + lq * 8];
        f32x4 lo = Ar[0], hi = Ar[1];
        uint4 up;
        up.x = pack2(lo[0], lo[1]); up.y = pack2(lo[2], lo[3]);
        up.z = pack2(hi[0], hi[1]); up.w = pack2(hi[2], hi[3]);
        a[kc] = *(short8*)&up;
    }

    f32x4 hacc[2];
#pragma unroll
    for (int nt = 0; nt < 2; nt++) hacc[nt] = (f32x4){0.f, 0.f, 0.f, 0.f};
#pragma unroll
    for (int nt = 0; nt < 2; nt++) {
        const short8* Br = Bt + (size_t)((wid * 2 + nt) * 16 + lm) * 16;
#pragma unroll
        for (int kc = 0; kc < 4; kc++)
            hacc[nt] = __builtin_amdgcn_mfma_f32_16x16x32_bf16(a[kc], Br[kc * 4 + lq], hacc[nt], 0, 0, 0);
    }

    // ---- Epilogue ----
#pragma unroll
    for (int nt = 0; nt < 2; nt++) {
        int col = (wid * 2 + nt) * 16 + lm;
        float bv = bias[col];
#pragma unroll
        for (int i = 0; i < 4; i++) {
            int row = r0 + lq * 4 + i;
            float v = fmaxf(hacc[nt][i] + bv, 0.f);
            if (SECOND) {
                Hs[lq * 4 + i][col] = f2bf(v);
            } else if (row < n) {
                out_h[(size_t)row * 128 + col] = f2bf(v);
            }
        }
    }

    if (SECOND) {
        __syncthreads();
        short8 a2[4];
#pragma unroll
        for (int kc = 0; kc < 4; kc++)
            a2[kc] = *(const short8*)&Hs[lm][kc * 32 + lq * 8];
        f32x4 yacc = (f32x4){0.f, 0.f, 0.f, 0.f};
        const short8* Br2 = Bt2 + (size_t)(wid * 16 + lm) * 16;
#pragma unroll
        for (int kc = 0; kc < 4; kc++)
            yacc = __builtin_amdgcn_mfma_f32_16x16x32_bf16(a2[kc], Br2[kc * 4 + lq], yacc, 0, 0, 0);
        int col = wid * 16 + lm;
#pragma unroll
        for (int i = 0; i < 4; i++) {
            int row = r0 + lq * 4 + i;
            if (row < n) out_y[(size_t)row * 64 + col] = f2bf(yacc[i]);
        }
    }
}

// ---------------- Final aggregation (D=64) + bo + log_softmax ----------------
// Block = 256 threads, 32 nodes. Same edge-parallel structure: 32 edge-groups x 8 chunks.

#define ECAP2 1536  // mean 512, >40 sigma headroom

__global__ __launch_bounds__(256) void agg_lsm(
    const uint4* __restrict__ x, float* __restrict__ out,
    const int* __restrict__ row_ptr, const unsigned short* __restrict__ csr,
    const float* __restrict__ bo, int n) {
    __shared__ float Asf[32][72];         // pitch 72 -> 16B-aligned rows
    __shared__ unsigned short eidx[ECAP2];
    __shared__ int rpl[33];

    int t = threadIdx.x;
    int g = t >> 3, c = t & 7;
    int r0 = blockIdx.x * 32;
    int node = r0 + g;

    int E0 = row_ptr[r0];                 // uniform
    int E1 = row_ptr[min(r0 + 32, n)];    // uniform
    int ecnt = E1 - E0;
    bool fits = (ecnt <= ECAP2);
    int scnt = fits ? ecnt : ECAP2;
    for (int i = t; i < scnt; i += 256) eidx[i] = csr[E0 + i];
    if (t < 33) rpl[t] = row_ptr[min(r0 + t, n)] - E0;

    // self term
    {
        f32x4 lo = {0.f, 0.f, 0.f, 0.f}, hi = {0.f, 0.f, 0.f, 0.f};
        if (node < n) {
            uint4 s0 = x[(size_t)node * 8 + c];
            lo[0] = bflo(s0.x); lo[1] = bfhi(s0.x); lo[2] = bflo(s0.y); lo[3] = bfhi(s0.y);
            hi[0] = bflo(s0.z); hi[1] = bfhi(s0.z); hi[2] = bflo(s0.w); hi[3] = bfhi(s0.w);
        }
        *(f32x4*)&Asf[g][c * 8] = lo;
        *(f32x4*)&Asf[g][c * 8 + 4] = hi;
    }
    __syncthreads();

    {
        int L = (ecnt + 31) >> 5;
        int j0 = g * L, jend = min(j0 + L, ecnt);
        if (j0 < jend) {
            int nd = ub_search<16>(rpl, j0);
            if (fits)
                edge_gather<72, 8>(Asf, rpl, x, c, j0, jend, nd,
                                   [&](int k) { return (int)eidx[k]; });
            else
                edge_gather<72, 8>(Asf, rpl, x, c, j0, jend, nd,
                                   [&](int k) { return (int)csr[E0 + k]; });
        }
    }
    __syncthreads();

    if (node >= n) return;

    const f32x4* Ar = (const f32x4*)&Asf[g][c * 8];
    f32x4 aLo = Ar[0], aHi = Ar[1];
    float acc[8] = {aLo[0], aLo[1], aLo[2], aLo[3], aHi[0], aHi[1], aHi[2], aHi[3]};

    const float4* bo4 = (const float4*)bo;
    float4 bA = bo4[c * 2], bB = bo4[c * 2 + 1];
    acc[0] += bA.x; acc[1] += bA.y; acc[2] += bA.z; acc[3] += bA.w;
    acc[4] += bB.x; acc[5] += bB.y; acc[6] += bB.z; acc[7] += bB.w;
    float m = acc[0];
#pragma unroll
    for (int j = 1; j < 8; j++) m = fmaxf(m, acc[j]);
#pragma unroll
    for (int off = 1; off < 8; off <<= 1) m = fmaxf(m, __shfl_xor(m, off, 64));
    float s = 0.f;
#pragma unroll
    for (int j = 0; j < 8; j++) s += __expf(acc[j] - m);
#pragma unroll
    for (int off = 1; off < 8; off <<= 1) s += __shfl_xor(s, off, 64);
    float ls = m + __logf(s);
    float4 o0 = make_float4(acc[0] - ls, acc[1] - ls, acc[2] - ls, acc[3] - ls);
    float4 o1 = make_float4(acc[4] - ls, acc[5] - ls, acc[6] - ls, acc[7] - ls);
    float4* op = (float4*)(out + (size_t)node * 64 + c * 8);
    op[0] = o0;
    op[1] = o1;
}

// ---------------- launch ----------------

extern "C" void kernel_launch(void* const* d_in, const int* in_sizes, int n_in,
                              void* d_out, int out_size, void* d_ws, size_t ws_size,
                              hipStream_t stream) {
    const float* feature = (const float*)d_in[0];
    const int*   edges   = (const int*)d_in[1];
    const float* W1 = (const float*)d_in[2];
    const float* b1 = (const float*)d_in[3];
    const float* Wh = (const float*)d_in[4];
    const float* bh = (const float*)d_in[5];
    const float* Wo = (const float*)d_in[6];
    const float* bo = (const float*)d_in[7];

    int n = in_sizes[0] / 128;  // 50000 (< 65536 for 16-bit src packing)
    int e = in_sizes[1] / 2;    // 800000
    const int* src = edges;
    const int* dst = edges + e;

    int nbkt = (n + 511) >> BSH;
    int nblk = (e + EPB - 1) / EPB;
    int nf4 = n * 32;
    int cvtb = (nf4 + 255) / 256;

    char* ws = (char*)d_ws;
    auto take = [&](size_t bytes) {
        char* p = ws;
        ws += (bytes + 255) & ~(size_t)255;
        return p;
    };
    int* cnt2d   = (int*)take((size_t)nbkt * nblk * 4);
    int* totals  = (int*)take((size_t)nbkt * 4);
    int* bbase   = (int*)take((size_t)(nbkt + 1) * 4);
    int* row_ptr = (int*)take((size_t)(n + 1) * 4);
    unsigned* pairs = (unsigned*)take((size_t)e * 4);
    unsigned short* csr = (unsigned short*)take((size_t)e * 2);
    unsigned short* featb = (unsigned short*)take((size_t)n * 128 * 2);
    unsigned short* hb    = (unsigned short*)take((size_t)n * 128 * 2);
    unsigned short* yb    = (unsigned short*)take((size_t)n * 64 * 2);
    unsigned short* W1t = (unsigned short*)take(128 * 128 * 2);
    unsigned short* Wht = (unsigned short*)take(128 * 128 * 2);
    unsigned short* Wot = (unsigned short*)take(64 * 128 * 2);

    // CSR build + conversions (binA co-scheduled with cvt/wt)
    mega1<<<nblk + cvtb + 160, 256, 0, stream>>>(
        dst, cnt2d, e, nbkt, nblk,
        (const float4*)feature, (uint2*)featb, cvtb, nf4,
        W1, Wh, Wo, W1t, Wht, Wot);
    scanB1<<<nbkt, 512, 0, stream>>>(cnt2d, totals, nblk);
    scanB2<<<1, 128, 0, stream>>>(totals, bbase, row_ptr, nbkt, n, e);
    binC<<<nblk, 256, 0, stream>>>(src, dst, cnt2d, bbase, pairs, e, nbkt, nblk);
    buildD<<<nbkt, 512, 0, stream>>>(pairs, totals, bbase, row_ptr, csr, n);

    int fblocks = (n + 15) / 16;

    // Layer 1: h1 = relu((x+agg(x))@W1+b1)
    fused_layer<false><<<fblocks, 256, 0, stream>>>(
        (const uint4*)featb, row_ptr, csr, (const short8*)W1t, b1,
        hb, nullptr, nullptr, n);

    // Layer 2 + layer-3 GEMM: h2 = relu((h1+agg(h1))@Wh+bh); y = h2@Wo
    fused_layer<true><<<fblocks, 256, 0, stream>>>(
        (const uint4*)hb, row_ptr, csr, (const short8*)Wht, bh,
        nullptr, (const short8*)Wot, yb, n);

    // out = log_softmax(y + agg(y) + bo)
    agg_lsm<<<(n + 31) / 32, 256, 0, stream>>>(
        (const uint4*)yb, (float*)d_out, row_ptr, csr, bo, n);
}

// Round 2
// 208.215 us; speedup vs baseline: 1.4919x; 1.4919x over previous
//
#include <hip/hip_runtime.h>

typedef short short8 __attribute__((ext_vector_type(8)));
typedef float f32x4 __attribute__((ext_vector_type(4)));

// ---------------- bf16 helpers ----------------

__device__ inline unsigned short f2bf(float f) {
    union { float f; unsigned u; } v; v.f = f;
    unsigned r = v.u + 0x7fffu + ((v.u >> 16) & 1u);
    return (unsigned short)(r >> 16);
}
__device__ inline unsigned pack2(float a, float b) {
    return (unsigned)f2bf(a) | ((unsigned)f2bf(b) << 16);
}
__device__ inline float bflo(unsigned u) { union { unsigned q; float f; } c; c.q = u << 16; return c.f; }
__device__ inline float bfhi(unsigned u) { union { unsigned q; float f; } c; c.q = u & 0xffff0000u; return c.f; }

#define ACC8(vv)                                     \
    acc[0] += bflo(vv.x); acc[1] += bfhi(vv.x);      \
    acc[2] += bflo(vv.y); acc[3] += bfhi(vv.y);      \
    acc[4] += bflo(vv.z); acc[5] += bfhi(vv.z);      \
    acc[6] += bflo(vv.w); acc[7] += bfhi(vv.w);

// Gather-accumulate over edges [beg,end); geti(k) supplies the row index
// (LDS-staged on the fast path). 16-wide batches keep 16 row loads in flight;
// the remainder is handled by ONE masked 16-wide batch (indices clamped to the
// last real edge -> duplicate loads coalesce onto already-fetched lines) so no
// serialized scalar-tail latencies remain.
template <int TPN, typename F>
__device__ __forceinline__ void gather_acc(float acc[8], const uint4* __restrict__ x,
                                           int lane, int beg, int end, F geti) {
    int k = beg;
    for (; k + 16 <= end; k += 16) {
        int idx[16];
#pragma unroll
        for (int j = 0; j < 16; j++) idx[j] = geti(k + j);
        uint4 v[16];
#pragma unroll
        for (int j = 0; j < 16; j++) v[j] = x[(size_t)idx[j] * TPN + lane];
#pragma unroll
        for (int j = 0; j < 16; j++) { ACC8(v[j]) }
    }
    int r = end - k;
    if (r > 0) {
        int lim = end - 1;
        int idx[16];
#pragma unroll
        for (int j = 0; j < 16; j++) idx[j] = geti(min(k + j, lim));
        uint4 v[16];
#pragma unroll
        for (int j = 0; j < 16; j++) v[j] = x[(size_t)idx[j] * TPN + lane];
#pragma unroll
        for (int j = 0; j < 16; j++) {
            if (k + j < end) { ACC8(v[j]) }
        }
    }
}

// ---------------- CSR build: atomic-free two-level bucket sort ----------------

#define EPB 2048
#define NE 8
#define BSH 9
#define MAXBKT 128
#define DCAP 10240

// mega1: binA (blocks [0,nblk)) + feature->bf16 cvt + weight transposes, one launch
__global__ __launch_bounds__(256) void mega1(const int* __restrict__ dst, int* __restrict__ cnt2d,
                                             int e, int nbkt, int nblk,
                                             const float4* __restrict__ feat, uint2* __restrict__ featb,
                                             int cvtb, int nf4,
                                             const float* __restrict__ W1, const float* __restrict__ Wh,
                                             const float* __restrict__ Wo,
                                             unsigned short* __restrict__ W1t, unsigned short* __restrict__ Wht,
                                             unsigned short* __restrict__ Wot) {
    __shared__ int hist[MAXBKT];
    int t = threadIdx.x, b = blockIdx.x;
    if (b < nblk) {
        for (int j = t; j < nbkt; j += 256) hist[j] = 0;
        __syncthreads();
        int base = b * EPB;
#pragma unroll
        for (int j = 0; j < NE; j++) {
            int idx = base + t + 256 * j;
            if (idx < e) atomicAdd(&hist[dst[idx] >> BSH], 1);
        }
        __syncthreads();
        for (int j = t; j < nbkt; j += 256) cnt2d[j * nblk + b] = hist[j];
    } else if (b < nblk + cvtb) {
        int i = (b - nblk) * 256 + t;
        if (i < nf4) {
            float4 v = feat[i];
            featb[i] = make_uint2(pack2(v.x, v.y), pack2(v.z, v.w));
        }
    } else {
        int i = (b - nblk - cvtb) * 256 + t;
        if (i < 16384) {
            int k = i >> 7, nn = i & 127;
            W1t[nn * 128 + k] = f2bf(W1[i]);
        } else if (i < 32768) {
            int j = i - 16384, k = j >> 7, nn = j & 127;
            Wht[nn * 128 + k] = f2bf(Wh[j]);
        } else if (i < 40960) {
            int j = i - 32768, k = j >> 6, nn = j & 63;
            Wot[nn * 128 + k] = f2bf(Wo[j]);
        }
    }
}

__global__ __launch_bounds__(512) void scanB1(int* __restrict__ cnt2d, int* __restrict__ totals, int nblk) {
    __shared__ int s[512];
    int t = threadIdx.x, b = blockIdx.x;
    int v = (t < nblk) ? cnt2d[b * nblk + t] : 0;
    s[t] = v;
    __syncthreads();
    for (int off = 1; off < 512; off <<= 1) {
        int u = (t >= off) ? s[t - off] : 0;
        __syncthreads();
        s[t] += u;
        __syncthreads();
    }
    if (t < nblk) cnt2d[b * nblk + t] = s[t] - v;
    if (t == nblk - 1) totals[b] = s[t];
}

__global__ __launch_bounds__(128) void scanB2(const int* __restrict__ totals, int* __restrict__ bbase,
                                              int* __restrict__ row_ptr, int nbkt, int n, int e) {
    __shared__ int s[128];
    int t = threadIdx.x;
    int v = (t < nbkt) ? totals[t] : 0;
    s[t] = v;
    __syncthreads();
    for (int off = 1; off < 128; off <<= 1) {
        int u = (t >= off) ? s[t - off] : 0;
        __syncthreads();
        s[t] += u;
        __syncthreads();
    }
    if (t < nbkt) bbase[t] = s[t] - v;
    if (t == 0) row_ptr[n] = e;
}

__global__ __launch_bounds__(256) void binC(const int* __restrict__ src, const int* __restrict__ dst,
                                            const int* __restrict__ cnt2d, const int* __restrict__ bbase,
                                            unsigned* __restrict__ pairs, int e, int nbkt, int nblk) {
    __shared__ int hist[MAXBKT], loff[MAXBKT], cur[MAXBKT], gb[MAXBKT];
    __shared__ int sc[256];
    __shared__ unsigned sorted[EPB];
    int t = threadIdx.x, blk = blockIdx.x;
    for (int b = t; b < nbkt; b += 256) hist[b] = 0;
    __syncthreads();
    int base = blk * EPB;
    int cnt = min(EPB, e - base);
    unsigned packed[NE];
    int bb[NE];
#pragma unroll
    for (int j = 0; j < NE; j++) {
        int idx = base + t + 256 * j;
        bb[j] = -1;
        if (idx < e) {
            unsigned s0 = (unsigned)src[idx], d = (unsigned)dst[idx];
            int b = (int)(d >> BSH);
            bb[j] = b;
            packed[j] = s0 | ((d & ((1u << BSH) - 1)) << 16) | ((unsigned)b << 25);
            atomicAdd(&hist[b], 1);
        }
    }
    __syncthreads();
    int v = (t < nbkt) ? hist[t] : 0;
    sc[t] = v;
    __syncthreads();
    for (int off = 1; off < 256; off <<= 1) {
        int u = (t >= off) ? sc[t - off] : 0;
        __syncthreads();
        sc[t] += u;
        __syncthreads();
    }
    if (t < nbkt) {
        int ex = sc[t] - v;
        loff[t] = ex;
        cur[t] = ex;
        gb[t] = bbase[t] + cnt2d[t * nblk + blk];
    }
    __syncthreads();
#pragma unroll
    for (int j = 0; j < NE; j++) {
        if (bb[j] >= 0) {
            int r = atomicAdd(&cur[bb[j]], 1);  // LDS only
            sorted[r] = packed[j];
        }
    }
    __syncthreads();
    for (int i = t; i < cnt; i += 256) {
        unsigned w = sorted[i];
        int b = (int)(w >> 25);
        pairs[gb[b] + (i - loff[b])] = w;
    }
}

__global__ __launch_bounds__(512) void buildD(const unsigned* __restrict__ pairs,
                                              const int* __restrict__ totals, const int* __restrict__ bbase,
                                              int* __restrict__ row_ptr, unsigned short* __restrict__ csr, int n) {
    __shared__ int hist[512], off[512];
    __shared__ unsigned short lcsr[DCAP];
    int t = threadIdx.x, b = blockIdx.x;
    int cnt = totals[b], base = bbase[b];
    hist[t] = 0;
    __syncthreads();
    for (int i = t; i < cnt; i += 512)
        atomicAdd(&hist[(pairs[base + i] >> 16) & 511], 1);
    __syncthreads();
    int v = hist[t];
    off[t] = v;
    __syncthreads();
    for (int o = 1; o < 512; o <<= 1) {
        int u = (t >= o) ? off[t - o] : 0;
        __syncthreads();
        off[t] += u;
        __syncthreads();
    }
    int excl = off[t] - v;
    int node = (b << BSH) + t;
    if (node < n) row_ptr[node] = base + excl;
    __syncthreads();
    hist[t] = excl;
    __syncthreads();
    for (int i = t; i < cnt; i += 512) {
        unsigned w = pairs[base + i];
        int r = atomicAdd(&hist[(w >> 16) & 511], 1);  // LDS only
        if (r < DCAP) lcsr[r] = (unsigned short)(w & 0xFFFFu);
    }
    __syncthreads();
    int lim = min(cnt, DCAP);
    for (int i = t; i < lim; i += 512) csr[base + i] = lcsr[i];
}

// ---------------- Fused layer (node-parallel gather + MFMA GEMM) ----------------
// Block = 256 threads = 16 nodes x 16 chunks. Tile rows exactly match one MFMA 16-row strip.

#define ECAP 1024   // block edge-index LDS cap; mean 256, >40 sigma headroom

template <bool SECOND>
__global__ __launch_bounds__(256) void fused_layer(
    const uint4* __restrict__ x, const int* __restrict__ row_ptr,
    const unsigned short* __restrict__ csr,
    const short8* __restrict__ Bt, const float* __restrict__ bias,
    unsigned short* __restrict__ out_h,   // !SECOND
    const short8* __restrict__ Bt2,       // SECOND
    unsigned short* __restrict__ out_y,   // SECOND
    int n) {
    __shared__ unsigned short As[16][136];  // +8 halves pad
    __shared__ unsigned short Hs[SECOND ? 16 : 1][SECOND ? 136 : 1];
    __shared__ unsigned short eidx[ECAP];

    int t = threadIdx.x;
    int nl = t >> 4, chunk = t & 15;
    int r0 = blockIdx.x * 16;
    int node = r0 + nl;

    // hoist independent global loads above the staging barrier (hide one round)
    int beg = 0, end = 0;
    uint4 s0 = make_uint4(0u, 0u, 0u, 0u);
    if (node < n) {
        beg = row_ptr[node];
        end = row_ptr[node + 1];
        s0 = x[(size_t)node * 16 + chunk];
    }

    // stage this block's (contiguous) edge indices into LDS
    int E0 = row_ptr[r0];
    int E1 = row_ptr[min(r0 + 16, n)];
    int ecnt = min(E1 - E0, ECAP);
    for (int i = t; i < ecnt; i += 256) eidx[i] = csr[E0 + i];
    __syncthreads();

    // ---- Phase 1: aggregation into registers ----
    float acc[8] = {0.f, 0.f, 0.f, 0.f, 0.f, 0.f, 0.f, 0.f};
    if (node < n) {
        ACC8(s0)
        if (end - E0 <= ECAP) {
            gather_acc<16>(acc, x, chunk, beg - E0, end - E0,
                           [&](int k) { return (int)eidx[k]; });
        } else {
            gather_acc<16>(acc, x, chunk, beg, end,
                           [&](int k) { return (int)csr[k]; });
        }
    }
    uint4 packed;
    packed.x = pack2(acc[0], acc[1]); packed.y = pack2(acc[2], acc[3]);
    packed.z = pack2(acc[4], acc[5]); packed.w = pack2(acc[6], acc[7]);
    ((uint4*)&As[nl][0])[chunk] = packed;
    __syncthreads();

    // ---- Phase 2: GEMM 16x128 @ 128x128 ----
    int wid = t >> 6, lane = t & 63;
    int lm = lane & 15, lq = lane >> 4;

    short8 a[4];
#pragma unroll
    for (int kc = 0; kc < 4; kc++)
        a[kc] = *(const short8*)&As[lm][kc * 32 + lq * 8];

    f32x4 hacc[2];
#pragma unroll
    for (int nt = 0; nt < 2; nt++) hacc[nt] = (f32x4){0.f, 0.f, 0.f, 0.f};
#pragma unroll
    for (int nt = 0; nt < 2; nt++) {
        const short8* Br = Bt + (size_t)((wid * 2 + nt) * 16 + lm) * 16;
#pragma unroll
        for (int kc = 0; kc < 4; kc++)
            hacc[nt] = __builtin_amdgcn_mfma_f32_16x16x32_bf16(a[kc], Br[kc * 4 + lq], hacc[nt], 0, 0, 0);
    }

    // ---- Epilogue ----
#pragma unroll
    for (int nt = 0; nt < 2; nt++) {
        int col = (wid * 2 + nt) * 16 + lm;
        float bv = bias[col];
#pragma unroll
        for (int i = 0; i < 4; i++) {
            int row = r0 + lq * 4 + i;
            float v = fmaxf(hacc[nt][i] + bv, 0.f);
            if (SECOND) {
                Hs[lq * 4 + i][col] = f2bf(v);
            } else if (row < n) {
                out_h[(size_t)row * 128 + col] = f2bf(v);
            }
        }
    }

    if (SECOND) {
        __syncthreads();
        short8 a2[4];
#pragma unroll
        for (int kc = 0; kc < 4; kc++)
            a2[kc] = *(const short8*)&Hs[lm][kc * 32 + lq * 8];
        f32x4 yacc = (f32x4){0.f, 0.f, 0.f, 0.f};
        const short8* Br2 = Bt2 + (size_t)(wid * 16 + lm) * 16;
#pragma unroll
        for (int kc = 0; kc < 4; kc++)
            yacc = __builtin_amdgcn_mfma_f32_16x16x32_bf16(a2[kc], Br2[kc * 4 + lq], yacc, 0, 0, 0);
        int col = wid * 16 + lm;
#pragma unroll
        for (int i = 0; i < 4; i++) {
            int row = r0 + lq * 4 + i;
            if (row < n) out_y[(size_t)row * 64 + col] = f2bf(yacc[i]);
        }
    }
}

// ---------------- Final aggregation (D=64) + bo + log_softmax ----------------
// Block = 256 threads = 32 nodes x 8 chunks.

#define ECAP2 1536  // mean 512, >40 sigma headroom

__global__ __launch_bounds__(256) void agg_lsm(
    const uint4* __restrict__ x, float* __restrict__ out,
    const int* __restrict__ row_ptr, const unsigned short* __restrict__ csr,
    const float* __restrict__ bo, int n) {
    __shared__ unsigned short eidx[ECAP2];
    int t = threadIdx.x;
    int r0 = blockIdx.x * 32;
    int node = r0 + (t >> 3), lane = t & 7;

    // hoist independent global loads above the staging barrier
    int beg = 0, end = 0;
    uint4 s0 = make_uint4(0u, 0u, 0u, 0u);
    if (node < n) {
        beg = row_ptr[node];
        end = row_ptr[node + 1];
        s0 = x[(size_t)node * 8 + lane];
    }

    int E0 = row_ptr[r0];
    int E1 = row_ptr[min(r0 + 32, n)];
    int ecnt = min(E1 - E0, ECAP2);
    for (int i = t; i < ecnt; i += 256) eidx[i] = csr[E0 + i];
    __syncthreads();

    if (node >= n) return;
    float acc[8] = { bflo(s0.x), bfhi(s0.x), bflo(s0.y), bfhi(s0.y),
                     bflo(s0.z), bfhi(s0.z), bflo(s0.w), bfhi(s0.w) };
    if (end - E0 <= ECAP2) {
        gather_acc<8>(acc, x, lane, beg - E0, end - E0,
                      [&](int k) { return (int)eidx[k]; });
    } else {
        gather_acc<8>(acc, x, lane, beg, end,
                      [&](int k) { return (int)csr[k]; });
    }

    const float4* bo4 = (const float4*)bo;
    float4 bA = bo4[lane * 2], bB = bo4[lane * 2 + 1];
    acc[0] += bA.x; acc[1] += bA.y; acc[2] += bA.z; acc[3] += bA.w;
    acc[4] += bB.x; acc[5] += bB.y; acc[6] += bB.z; acc[7] += bB.w;
    float m = acc[0];
#pragma unroll
    for (int j = 1; j < 8; j++) m = fmaxf(m, acc[j]);
#pragma unroll
    for (int off = 1; off < 8; off <<= 1) m = fmaxf(m, __shfl_xor(m, off, 64));
    float s = 0.f;
#pragma unroll
    for (int j = 0; j < 8; j++) s += __expf(acc[j] - m);
#pragma unroll
    for (int off = 1; off < 8; off <<= 1) s += __shfl_xor(s, off, 64);
    float ls = m + __logf(s);
    float4 o0 = make_float4(acc[0] - ls, acc[1] - ls, acc[2] - ls, acc[3] - ls);
    float4 o1 = make_float4(acc[4] - ls, acc[5] - ls, acc[6] - ls, acc[7] - ls);
    float4* op = (float4*)(out + (size_t)node * 64 + lane * 8);
    op[0] = o0;
    op[1] = o1;
}

// ---------------- launch ----------------

extern "C" void kernel_launch(void* const* d_in, const int* in_sizes, int n_in,
                              void* d_out, int out_size, void* d_ws, size_t ws_size,
                              hipStream_t stream) {
    const float* feature = (const float*)d_in[0];
    const int*   edges   = (const int*)d_in[1];
    const float* W1 = (const float*)d_in[2];
    const float* b1 = (const float*)d_in[3];
    const float* Wh = (const float*)d_in[4];
    const float* bh = (const float*)d_in[5];
    const float* Wo = (const float*)d_in[6];
    const float* bo = (const float*)d_in[7];

    int n = in_sizes[0] / 128;  // 50000 (< 65536 for 16-bit src packing)
    int e = in_sizes[1] / 2;    // 800000
    const int* src = edges;
    const int* dst = edges + e;

    int nbkt = (n + 511) >> BSH;
    int nblk = (e + EPB - 1) / EPB;
    int nf4 = n * 32;
    int cvtb = (nf4 + 255) / 256;

    char* ws = (char*)d_ws;
    auto take = [&](size_t bytes) {
        char* p = ws;
        ws += (bytes + 255) & ~(size_t)255;
        return p;
    };
    int* cnt2d   = (int*)take((size_t)nbkt * nblk * 4);
    int* totals  = (int*)take((size_t)nbkt * 4);
    int* bbase   = (int*)take((size_t)(nbkt + 1) * 4);
    int* row_ptr = (int*)take((size_t)(n + 1) * 4);
    unsigned* pairs = (unsigned*)take((size_t)e * 4);
    unsigned short* csr = (unsigned short*)take((size_t)e * 2);
    unsigned short* featb = (unsigned short*)take((size_t)n * 128 * 2);
    unsigned short* hb    = (unsigned short*)take((size_t)n * 128 * 2);
    unsigned short* yb    = (unsigned short*)take((size_t)n * 64 * 2);
    unsigned short* W1t = (unsigned short*)take(128 * 128 * 2);
    unsigned short* Wht = (unsigned short*)take(128 * 128 * 2);
    unsigned short* Wot = (unsigned short*)take(64 * 128 * 2);

    // CSR build + conversions (binA co-scheduled with cvt/wt)
    mega1<<<nblk + cvtb + 160, 256, 0, stream>>>(
        dst, cnt2d, e, nbkt, nblk,
        (const float4*)feature, (uint2*)featb, cvtb, nf4,
        W1, Wh, Wo, W1t, Wht, Wot);
    scanB1<<<nbkt, 512, 0, stream>>>(cnt2d, totals, nblk);
    scanB2<<<1, 128, 0, stream>>>(totals, bbase, row_ptr, nbkt, n, e);
    binC<<<nblk, 256, 0, stream>>>(src, dst, cnt2d, bbase, pairs, e, nbkt, nblk);
    buildD<<<nbkt, 512, 0, stream>>>(pairs, totals, bbase, row_ptr, csr, n);

    int fblocks = (n + 15) / 16;

    // Layer 1: h1 = relu((x+agg(x))@W1+b1)
    fused_layer<false><<<fblocks, 256, 0, stream>>>(
        (const uint4*)featb, row_ptr, csr, (const short8*)W1t, b1,
        hb, nullptr, nullptr, n);

    // Layer 2 + layer-3 GEMM: h2 = relu((h1+agg(h1))@Wh+bh); y = h2@Wo
    fused_layer<true><<<fblocks, 256, 0, stream>>>(
        (const uint4*)hb, row_ptr, csr, (const short8*)Wht, bh,
        nullptr, (const short8*)Wot, yb, n);

    // out = log_softmax(y + agg(y) + bo)
    agg_lsm<<<(n + 31) / 32, 256, 0, stream>>>(
        (const uint4*)yb, (float*)d_out, row_ptr, csr, bo, n);
}